// Round 6
// baseline (28.619 us; speedup 1.0000x reference)
//
#include <hip/hip_runtime.h>

// ColBERT maxsim via MFMA + whole-doc bf16 LDS staging (single phase).
// out[b] = sum_q max_k ( mask[b,k] ? <D[b,k,:], Q[b/8,q,:]> : -9999 )
// B*NWAY=1024 docs, DLEN=220, QLEN=32, DIM=128.
//
// Round-5 lesson: 2 stage->compute cycles per block = 3 barrier drains; HBM
// idles at each boundary -> 4.4 TB/s. Round-6: stage ALL 220 rows (bf16,
// 55 KB) in one pass with 512 threads, ONE syncthreads, then 7 waves compute
// one 32-token tile each. D chunk c is at byte 16*c (fully linear stream);
// each thread loads 14 chunks in two 7-deep float4 groups.
// LDS 57 KB -> 2 blocks/CU (16 waves/CU) hides load latency via TLP.
//
// LDS rows are 256B bf16: XOR-swizzle byte ^= ((row&7)<<4) kills the 32-way
// ds_read_b128 bank conflict (write side 8B-aligned, read side 16B-aligned,
// both preserved by XOR of bits 4-6).
//
// MFMA mfma_f32_32x32x16_bf16: A-frag lane(c=lane&31,g=lane>>5) holds row c,
// k=ks*16+g*8..+8; same k-map used for Q => layout-safe (K-perm invariant).
// C/D layout (m74/m101): col(q)=lane&31, row(token)=(reg&3)+8*(reg>>2)+4*g.

#define QLEN   32
#define DIM    128
#define DLEN   220
#define NWAVES 8
#define NTILES 7
#define TOTCH  (DLEN * 32)   // 7040 16B f32 chunks per doc

typedef __attribute__((ext_vector_type(8)))  short bf16x8;
typedef __attribute__((ext_vector_type(16))) float f32x16;

__device__ __forceinline__ short f2bf(float f) {
    __bf16 h = (__bf16)f;                      // RNE hardware convert
    return __builtin_bit_cast(short, h);
}

__device__ __forceinline__ bf16x8 cvt8(const float4& a, const float4& b) {
    bf16x8 r;
    r[0] = f2bf(a.x); r[1] = f2bf(a.y); r[2] = f2bf(a.z); r[3] = f2bf(a.w);
    r[4] = f2bf(b.x); r[5] = f2bf(b.y); r[6] = f2bf(b.z); r[7] = f2bf(b.w);
    return r;
}

__global__ __launch_bounds__(512, 4)
void colbert_mfma(const float* __restrict__ Q,
                  const float* __restrict__ D,
                  const int*   __restrict__ Dm,
                  float* __restrict__ out)
{
    // XCD swizzle (bijective: gridDim.x = 1024 % 8 == 0): the 8 docs sharing a
    // Q tile land on one XCD's L2 -> Q HBM traffic ~2 MB instead of 16 MB.
    const int cpx = gridDim.x >> 3;
    const int o   = blockIdx.x;
    const int b   = (o & 7) * cpx + (o >> 3);

    const int tid  = threadIdx.x;
    const int wave = tid >> 6;
    const int lane = tid & 63;
    const int qb   = b >> 3;            // nway = 8

    const int col = lane & 31;          // A row-in-tile / B col (q)
    const int g   = lane >> 5;          // k-group

    __shared__ __align__(16) short lds[DLEN * DIM];   // 55 KB bf16, swizzled rows
    __shared__ float red[NWAVES][QLEN];

    // ---- Q fragment: strided loads, tiny volume (XCD-L2 resident) ----
    const float* __restrict__ qrow = Q + ((size_t)qb * QLEN + col) * DIM;
    bf16x8 bq[8];
#pragma unroll
    for (int ks = 0; ks < 8; ++ks) {
        const float4 x = *reinterpret_cast<const float4*>(qrow + ks * 16 + g * 8);
        const float4 y = *reinterpret_cast<const float4*>(qrow + ks * 16 + g * 8 + 4);
        bq[ks] = cvt8(x, y);
    }

    const float* __restrict__ dbase = D + (size_t)b * DLEN * DIM;
    const int*   __restrict__ dmb   = Dm + (size_t)b * DLEN;

    // ---- stage whole doc: linear f32 stream -> cvt -> swizzled bf16 LDS ----
    // chunk c (16B) lives at float offset 4*c; thread t owns c = t + u*512.
#pragma unroll
    for (int grp = 0; grp < 2; ++grp) {
        float4 v[7];
#pragma unroll
        for (int u = 0; u < 7; ++u) {
            const int c  = tid + (grp * 7 + u) * 512;
            const int cl = (c < TOTCH) ? c : 0;            // clamp: always load
            v[u] = *reinterpret_cast<const float4*>(dbase + (size_t)cl * 4);
        }
#pragma unroll
        for (int u = 0; u < 7; ++u) {
            const int c = tid + (grp * 7 + u) * 512;
            if (c < TOTCH) {
                const int row = c >> 5, cir = c & 31;
                short4 s;
                s.x = f2bf(v[u].x); s.y = f2bf(v[u].y);
                s.z = f2bf(v[u].z); s.w = f2bf(v[u].w);
                const int byte = row * 256 + ((cir * 8) ^ ((row & 7) << 4));
                *reinterpret_cast<short4*>(reinterpret_cast<char*>(lds) + byte) = s;
            }
        }
    }
    __syncthreads();

    // ---- compute: one 32-token tile per wave (wave 7 idles) ----
    float best = -9999.0f;
    if (wave < NTILES) {
        const int tbase = wave * 32;
        int rloc = tbase + col;
        if (rloc > DLEN - 1) rloc = DLEN - 1;              // clamp; masked below
        const int rsw = (rloc & 7) << 4;

        f32x16 acc = {};
#pragma unroll
        for (int ks = 0; ks < 8; ++ks) {
            const int byte = rloc * 256 + ((ks * 32 + g * 16) ^ rsw);
            const bf16x8 a = *reinterpret_cast<const bf16x8*>(
                                 reinterpret_cast<const char*>(lds) + byte);
            acc = __builtin_amdgcn_mfma_f32_32x32x16_bf16(a, bq[ks], acc, 0, 0, 0);
        }

        // mask + fold into running per-(q=col) max.
        // lane's acc reg r covers token tbase + (r&3) + 8*(r>>2) + 4*g
#pragma unroll
        for (int p = 0; p < 4; ++p) {
            const int r4  = tbase + p * 8 + g * 4;
            const int r4c = (r4 <= DLEN - 4) ? r4 : (DLEN - 4);
            const int4 m4 = *reinterpret_cast<const int4*>(dmb + r4c);
            const float v0 = (r4 + 0 < DLEN && m4.x > 0) ? acc[4 * p + 0] : -9999.0f;
            const float v1 = (r4 + 1 < DLEN && m4.y > 0) ? acc[4 * p + 1] : -9999.0f;
            const float v2 = (r4 + 2 < DLEN && m4.z > 0) ? acc[4 * p + 2] : -9999.0f;
            const float v3 = (r4 + 3 < DLEN && m4.w > 0) ? acc[4 * p + 3] : -9999.0f;
            best = fmaxf(best, fmaxf(fmaxf(v0, v1), fmaxf(v2, v3)));
        }
    }

    // combine the two k-group token-halves (lanes l and l^32 share q=col)
    best = fmaxf(best, __shfl_xor(best, 32, 64));

    // ---- cross-wave max, then sum over q ----
    if (lane < 32) red[wave][col] = best;
    __syncthreads();

    if (tid < QLEN) {
        float m = red[0][tid];
#pragma unroll
        for (int w = 1; w < NWAVES; ++w) m = fmaxf(m, red[w][tid]);
#pragma unroll
        for (int off = 16; off > 0; off >>= 1) m += __shfl_xor(m, off, 32);
        if (tid == 0) out[b] = m;
    }
}

extern "C" void kernel_launch(void* const* d_in, const int* in_sizes, int n_in,
                              void* d_out, int out_size, void* d_ws, size_t ws_size,
                              hipStream_t stream)
{
    const float* Q  = (const float*)d_in[0];
    const float* D  = (const float*)d_in[1];
    const int*   Dm = (const int*)d_in[2];
    float* outp = (float*)d_out;
    const int ndocs = out_size;   // B*NWAY = 1024
    colbert_mfma<<<ndocs, NWAVES * 64, 0, stream>>>(Q, D, Dm, outp);
}

// Round 7
// 26.511 us; speedup vs baseline: 1.0795x; 1.0795x over previous
//
#include <hip/hip_runtime.h>

// ColBERT maxsim via MFMA + LDS staging of BOTH operands.
// out[b] = sum_q max_k ( mask[b,k] ? <D[b,k,:], Q[b/8,q,:]> : -9999 )
// B*NWAY=1024 docs, DLEN=220, QLEN=32, DIM=128.
//
// Round-6 lesson: D was LDS-staged but Q fragments stayed per-lane 512B-stride
// gathers, re-issued by EVERY wave: ~2048 L2 transactions/block vs D's ~880.
// Transaction-rate bound -> plateau at 4.3 TB/s. Round-7: Q also goes
// global(coalesced) -> bf16 -> swizzled LDS; waves read bq via ds_read_b128.
// Strided transactions per block drop ~3x.
//
// Skeleton = R5 winner: 256 thr / 4 waves, doc in 2 chunks (128+92 rows),
// LDS exactly 40960 B (32K D + 8K Q; red[] aliases Q after last bq read)
// -> 4 blocks/CU. T14: chunk-1 global loads issue before chunk-0 compute.
//
// XOR swizzle byte ^= ((row&7)<<4) on 256B bf16 rows kills the 32-way
// ds_read_b128 bank conflict (write 8B-aligned, read 16B-aligned, preserved).
// MFMA mfma_f32_32x32x16_bf16; same k-map for A and B => layout-safe.
// C/D layout (m74/m101): col(q)=lane&31, row(token)=(reg&3)+8*(reg>>2)+4*g.

#define QLEN   32
#define DIM    128
#define DLEN   220
#define NWAVES 4
#define CR0    128
#define CR1    (DLEN - CR0)     // 92

typedef __attribute__((ext_vector_type(8)))  short bf16x8;
typedef __attribute__((ext_vector_type(16))) float f32x16;

__device__ __forceinline__ short f2bf(float f) {
    __bf16 h = (__bf16)f;                      // RNE hardware convert
    return __builtin_bit_cast(short, h);
}

__device__ __forceinline__ short4 cvt4(const float4& v) {
    short4 s;
    s.x = f2bf(v.x); s.y = f2bf(v.y); s.z = f2bf(v.z); s.w = f2bf(v.w);
    return s;
}

__global__ __launch_bounds__(256, 4)
void colbert_mfma(const float* __restrict__ Q,
                  const float* __restrict__ D,
                  const int*   __restrict__ Dm,
                  float* __restrict__ out)
{
    // XCD swizzle (bijective: gridDim.x = 1024 % 8 == 0): docs sharing a Q
    // tile land on one XCD's L2.
    const int cpx = gridDim.x >> 3;
    const int o   = blockIdx.x;
    const int b   = (o & 7) * cpx + (o >> 3);

    const int tid  = threadIdx.x;
    const int wave = tid >> 6;
    const int lane = tid & 63;
    const int qb   = b >> 3;            // nway = 8

    const int col = lane & 31;          // A row-in-tile / B col (q)
    const int g   = lane >> 5;          // k-group

    // Exactly 40960 B so 4 blocks/CU: [0,32768) D tile, [32768,40960) Q tile;
    // red[] aliases the Q region (all bq reads happen 2 barriers earlier).
    __shared__ __align__(16) char smem[40960];
    char* __restrict__ dl = smem;
    char* __restrict__ ql = smem + 32768;
    float (*red)[QLEN] = reinterpret_cast<float (*)[QLEN]>(smem + 32768);

    const float* __restrict__ qbase = Q + (size_t)qb * QLEN * DIM;
    const float* __restrict__ dbase = D + (size_t)b * DLEN * DIM;
    const int*   __restrict__ dmb   = Dm + (size_t)b * DLEN;

    // ---- issue ALL stage-0 loads: Q (4 chunks/thr) + D chunk0 (16/thr) ----
    float4 qv[4];
#pragma unroll
    for (int u = 0; u < 4; ++u)
        qv[u] = *reinterpret_cast<const float4*>(qbase + (size_t)(tid + u * 256) * 4);
    float4 dv[16];
#pragma unroll
    for (int u = 0; u < 16; ++u)
        dv[u] = *reinterpret_cast<const float4*>(dbase + (size_t)(tid + u * 256) * 4);

    // ---- swizzled bf16 writes ----
#pragma unroll
    for (int u = 0; u < 4; ++u) {
        const int c = tid + u * 256, row = c >> 5, cir = c & 31;
        const int byte = row * 256 + ((cir * 8) ^ ((row & 7) << 4));
        *reinterpret_cast<short4*>(ql + byte) = cvt4(qv[u]);
    }
#pragma unroll
    for (int u = 0; u < 16; ++u) {
        const int c = tid + u * 256, row = c >> 5, cir = c & 31;
        const int byte = row * 256 + ((cir * 8) ^ ((row & 7) << 4));
        *reinterpret_cast<short4*>(dl + byte) = cvt4(dv[u]);
    }
    __syncthreads();

    // ---- bq fragments from Q-LDS (one-time, 8 ds_read_b128) ----
    bf16x8 bq[8];
    {
        const int rsw = (col & 7) << 4;
#pragma unroll
        for (int ks = 0; ks < 8; ++ks) {
            const int byte = col * 256 + ((ks * 32 + g * 16) ^ rsw);
            bq[ks] = *reinterpret_cast<const bf16x8*>(ql + byte);
        }
    }

    // ---- T14: issue chunk-1 global loads BEFORE chunk-0 compute ----
    float4 ev[12];
#pragma unroll
    for (int u = 0; u < 12; ++u) {
        const int c  = tid + u * 256;
        const int cl = (c < CR1 * 32) ? c : (CR1 * 32 - 1);
        ev[u] = *reinterpret_cast<const float4*>(dbase + (size_t)(CR0 * 32 + cl) * 4);
    }

    float best = -9999.0f;

    // ---- compute chunk0: 128 rows = 4 tiles, one per wave ----
    {
        const int tloc = wave * 32;
        const int rloc = tloc + col;              // < 128, no clamp
        const int rsw  = (rloc & 7) << 4;
        f32x16 acc = {};
#pragma unroll
        for (int ks = 0; ks < 8; ++ks) {
            const int byte = rloc * 256 + ((ks * 32 + g * 16) ^ rsw);
            const bf16x8 a = *reinterpret_cast<const bf16x8*>(dl + byte);
            acc = __builtin_amdgcn_mfma_f32_32x32x16_bf16(a, bq[ks], acc, 0, 0, 0);
        }
        // tokens all < 128 < DLEN: only the mask check needed
#pragma unroll
        for (int p = 0; p < 4; ++p) {
            const int r4 = tloc + p * 8 + g * 4;
            const int4 m4 = *reinterpret_cast<const int4*>(dmb + r4);
            const float v0 = (m4.x > 0) ? acc[4 * p + 0] : -9999.0f;
            const float v1 = (m4.y > 0) ? acc[4 * p + 1] : -9999.0f;
            const float v2 = (m4.z > 0) ? acc[4 * p + 2] : -9999.0f;
            const float v3 = (m4.w > 0) ? acc[4 * p + 3] : -9999.0f;
            best = fmaxf(best, fmaxf(fmaxf(v0, v1), fmaxf(v2, v3)));
        }
    }
    __syncthreads();                   // chunk0 reads done before overwrite

    // ---- write chunk1 into D-LDS ----
#pragma unroll
    for (int u = 0; u < 12; ++u) {
        const int c = tid + u * 256;
        if (c < CR1 * 32) {
            const int row = c >> 5, cir = c & 31;
            const int byte = row * 256 + ((cir * 8) ^ ((row & 7) << 4));
            *reinterpret_cast<short4*>(dl + byte) = cvt4(ev[u]);
        }
    }
    __syncthreads();

    // ---- compute chunk1: 92 rows = 3 tiles (wave 3 idle) ----
    if (wave < 3) {
        const int tloc = wave * 32;
        int rloc = tloc + col;
        if (rloc > CR1 - 1) rloc = CR1 - 1;        // clamp; rejected below
        const int rsw = (rloc & 7) << 4;
        f32x16 acc = {};
#pragma unroll
        for (int ks = 0; ks < 8; ++ks) {
            const int byte = rloc * 256 + ((ks * 32 + g * 16) ^ rsw);
            const bf16x8 a = *reinterpret_cast<const bf16x8*>(dl + byte);
            acc = __builtin_amdgcn_mfma_f32_32x32x16_bf16(a, bq[ks], acc, 0, 0, 0);
        }
#pragma unroll
        for (int p = 0; p < 4; ++p) {
            const int r4  = CR0 + tloc + p * 8 + g * 4;     // global token base
            const int r4c = (r4 <= DLEN - 4) ? r4 : (DLEN - 4);
            const int4 m4 = *reinterpret_cast<const int4*>(dmb + r4c);
            const float v0 = (r4 + 0 < DLEN && m4.x > 0) ? acc[4 * p + 0] : -9999.0f;
            const float v1 = (r4 + 1 < DLEN && m4.y > 0) ? acc[4 * p + 1] : -9999.0f;
            const float v2 = (r4 + 2 < DLEN && m4.z > 0) ? acc[4 * p + 2] : -9999.0f;
            const float v3 = (r4 + 3 < DLEN && m4.w > 0) ? acc[4 * p + 3] : -9999.0f;
            best = fmaxf(best, fmaxf(fmaxf(v0, v1), fmaxf(v2, v3)));
        }
    }

    // combine the two k-group token-halves (lanes l and l^32 share q=col)
    best = fmaxf(best, __shfl_xor(best, 32, 64));

    // ---- cross-wave max (red aliases Q-LDS: bq long since consumed) ----
    if (lane < 32) red[wave][col] = best;
    __syncthreads();

    if (tid < QLEN) {
        float m = red[0][tid];
#pragma unroll
        for (int w = 1; w < NWAVES; ++w) m = fmaxf(m, red[w][tid]);
#pragma unroll
        for (int off = 16; off > 0; off >>= 1) m += __shfl_xor(m, off, 32);
        if (tid == 0) out[b] = m;
    }
}

extern "C" void kernel_launch(void* const* d_in, const int* in_sizes, int n_in,
                              void* d_out, int out_size, void* d_ws, size_t ws_size,
                              hipStream_t stream)
{
    const float* Q  = (const float*)d_in[0];
    const float* D  = (const float*)d_in[1];
    const int*   Dm = (const int*)d_in[2];
    float* outp = (float*)d_out;
    const int ndocs = out_size;   // B*NWAY = 1024
    colbert_mfma<<<ndocs, NWAVES * 64, 0, stream>>>(Q, D, Dm, outp);
}

// Round 8
// 21.724 us; speedup vs baseline: 1.3174x; 1.2203x over previous
//
#include <hip/hip_runtime.h>

// ColBERT maxsim via MFMA + masked-row compaction.
// out[b] = sum_q max_k ( mask[b,k] ? <D[b,k,:], Q[b/8,q,:]> : -9999 )
// B*NWAY=1024 docs, DLEN=220, QLEN=32, DIM=128.
//
// KEY INSIGHT (round 8): D_mask zeroes ~50% of rows, and masked rows are
// exactly discarded by the max (-9999 never wins; best is init'd to -9999,
// which also reproduces the all-masked case). So: compact unmasked row
// indices per doc, stage ONLY those rows into LDS (each kept row = 512 B
// contiguous = 4 full 128B lines, still coalesced), and validity-test the
// compacted index in the epilogue instead of re-reading the mask.
// D HBM traffic halves: 115 MB -> ~58 MB. Rounds 5-7 plateaued at 26.5 us
// (~75-80% stream duty); halving bytes beats any further duty-cycle tweak.
//
// Skeleton = R5 winner: 256 thr / 4 waves / 4 blocks/CU; chunk0 = first
// min(nc,128) kept rows (covers ~99.4% of docs entirely), rare chunk1 for
// nc>128. XOR swizzle byte ^= ((row&7)<<4) on 256B bf16 LDS rows kills the
// 32-way ds_read_b128 bank conflict. Q fragments stay direct strided loads
// (R7 proved LDS-staging them is perf-null).
//
// MFMA mfma_f32_32x32x16_bf16; same k-map for A and B => layout-safe.
// C/D layout (m74/m101): col(q)=lane&31, row(token)=(reg&3)+8*(reg>>2)+4*g.

#define QLEN   32
#define DIM    128
#define DLEN   220
#define NWAVES 4
#define C0MAX  128

typedef __attribute__((ext_vector_type(8)))  short bf16x8;
typedef __attribute__((ext_vector_type(16))) float f32x16;

__device__ __forceinline__ short f2bf(float f) {
    __bf16 h = (__bf16)f;                      // RNE hardware convert
    return __builtin_bit_cast(short, h);
}

__device__ __forceinline__ short4 cvt4(const float4& v) {
    short4 s;
    s.x = f2bf(v.x); s.y = f2bf(v.y); s.z = f2bf(v.z); s.w = f2bf(v.w);
    return s;
}

__device__ __forceinline__ bf16x8 cvt8(const float4& a, const float4& b) {
    bf16x8 r;
    r[0] = f2bf(a.x); r[1] = f2bf(a.y); r[2] = f2bf(a.z); r[3] = f2bf(a.w);
    r[4] = f2bf(b.x); r[5] = f2bf(b.y); r[6] = f2bf(b.z); r[7] = f2bf(b.w);
    return r;
}

__global__ __launch_bounds__(256, 4)
void colbert_mfma(const float* __restrict__ Q,
                  const float* __restrict__ D,
                  const int*   __restrict__ Dm,
                  float* __restrict__ out)
{
    // XCD swizzle (bijective: gridDim.x = 1024 % 8 == 0): docs sharing a Q
    // tile land on one XCD's L2.
    const int cpx = gridDim.x >> 3;
    const int o   = blockIdx.x;
    const int b   = (o & 7) * cpx + (o >> 3);

    const int tid  = threadIdx.x;
    const int wave = tid >> 6;
    const int lane = tid & 63;
    const int qb   = b >> 3;            // nway = 8

    const int col = lane & 31;          // A row-in-tile / B col (q)
    const int g   = lane >> 5;          // k-group

    __shared__ __align__(16) short dl[C0MAX * DIM];   // 32 KB staged bf16 rows
    __shared__ short list[DLEN + 4];                   // compacted row indices
    __shared__ int   wcnt[NWAVES];
    __shared__ int   s_nc;
    __shared__ float red[NWAVES][QLEN];

    const float* __restrict__ dbase = D + (size_t)b * DLEN * DIM;

    // ---- Q fragments: direct strided loads (tiny, L2-resident; issue first
    //      so they're in flight during mask/compaction) ----
    const float* __restrict__ qrow = Q + ((size_t)qb * QLEN + col) * DIM;
    bf16x8 bq[8];
#pragma unroll
    for (int ks = 0; ks < 8; ++ks) {
        const float4 x = *reinterpret_cast<const float4*>(qrow + ks * 16 + g * 8);
        const float4 y = *reinterpret_cast<const float4*>(qrow + ks * 16 + g * 8 + 4);
        bq[ks] = cvt8(x, y);
    }

    // ---- load mask + compact kept row indices (order-preserving) ----
    int mv = 0;
    if (tid < DLEN) mv = (Dm[(size_t)b * DLEN + tid] > 0) ? 1 : 0;
    const unsigned long long bal = __ballot(mv);
    const int prefix = __popcll(bal & ((1ull << lane) - 1ull));
    if (lane == 0) wcnt[wave] = __popcll(bal);
    __syncthreads();
    int base = 0;
#pragma unroll
    for (int w = 0; w < NWAVES; ++w) base += (w < wave) ? wcnt[w] : 0;
    if (mv) list[base + prefix] = (short)tid;
    if (tid == 0) s_nc = wcnt[0] + wcnt[1] + wcnt[2] + wcnt[3];
    __syncthreads();

    const int nc = s_nc;                 // kept rows, ~Binom(220,1/2) ~ 110
    const int c0 = (nc < C0MAX) ? nc : C0MAX;

    // ---- stage chunk0: only kept rows, coalesced 512B-per-row reads ----
    {
        const int nch = c0 * 32;         // 16B chunks
        for (int i = tid; i < nch; i += 512) {
            const int i2   = i + 256;
            const int r1   = list[i >> 5], c1i = i & 31;
            float4 v1 = *reinterpret_cast<const float4*>(
                            dbase + (size_t)r1 * DIM + c1i * 4);
            float4 v2;
            int r2 = 0, c2i = 0;
            if (i2 < nch) {
                r2  = list[i2 >> 5];  c2i = i2 & 31;
                v2  = *reinterpret_cast<const float4*>(
                          dbase + (size_t)r2 * DIM + c2i * 4);
            }
            {
                const int lr = i >> 5;
                const int byte = lr * 256 + ((c1i * 8) ^ ((lr & 7) << 4));
                *reinterpret_cast<short4*>(reinterpret_cast<char*>(dl) + byte) = cvt4(v1);
            }
            if (i2 < nch) {
                const int lr = i2 >> 5;
                const int byte = lr * 256 + ((c2i * 8) ^ ((lr & 7) << 4));
                *reinterpret_cast<short4*>(reinterpret_cast<char*>(dl) + byte) = cvt4(v2);
            }
        }
    }
    __syncthreads();

    float best = -9999.0f;

    // ---- compute chunk0: ceil(c0/32) tiles, one per wave ----
    {
        const int ntiles = (c0 + 31) >> 5;
        if (wave < ntiles) {
            const int tloc = wave * 32;
            int rloc = tloc + col;
            if (rloc >= c0) rloc = 0;              // clamp; rejected below
            const int rsw = (rloc & 7) << 4;
            f32x16 acc = {};
#pragma unroll
            for (int ks = 0; ks < 8; ++ks) {
                const int byte = rloc * 256 + ((ks * 32 + g * 16) ^ rsw);
                const bf16x8 a = *reinterpret_cast<const bf16x8*>(
                                     reinterpret_cast<const char*>(dl) + byte);
                acc = __builtin_amdgcn_mfma_f32_32x32x16_bf16(a, bq[ks], acc, 0, 0, 0);
            }
            // validity: compacted local index < c0 (no mask reads needed)
#pragma unroll
            for (int p = 0; p < 4; ++p) {
                const int i4 = tloc + p * 8 + g * 4;   // local idx of acc[4p+0]
                const float v0 = (i4 + 0 < c0) ? acc[4 * p + 0] : -9999.0f;
                const float v1 = (i4 + 1 < c0) ? acc[4 * p + 1] : -9999.0f;
                const float v2 = (i4 + 2 < c0) ? acc[4 * p + 2] : -9999.0f;
                const float v3 = (i4 + 3 < c0) ? acc[4 * p + 3] : -9999.0f;
                best = fmaxf(best, fmaxf(fmaxf(v0, v1), fmaxf(v2, v3)));
            }
        }
    }

    // ---- rare chunk1 (nc > 128; ~0.6% of docs): same flow, block-uniform ----
    const int cr1 = nc - c0;
    if (cr1 > 0) {
        __syncthreads();                 // chunk0 reads done before overwrite
        const int nch = cr1 * 32;
        for (int i = tid; i < nch; i += 256) {
            const int row = list[c0 + (i >> 5)], cir = i & 31;
            const float4 v = *reinterpret_cast<const float4*>(
                                 dbase + (size_t)row * DIM + cir * 4);
            const int lr = i >> 5;
            const int byte = lr * 256 + ((cir * 8) ^ ((lr & 7) << 4));
            *reinterpret_cast<short4*>(reinterpret_cast<char*>(dl) + byte) = cvt4(v);
        }
        __syncthreads();

        const int ntiles = (cr1 + 31) >> 5;
        if (wave < ntiles) {
            const int tloc = wave * 32;
            int rloc = tloc + col;
            if (rloc >= cr1) rloc = 0;
            const int rsw = (rloc & 7) << 4;
            f32x16 acc = {};
#pragma unroll
            for (int ks = 0; ks < 8; ++ks) {
                const int byte = rloc * 256 + ((ks * 32 + g * 16) ^ rsw);
                const bf16x8 a = *reinterpret_cast<const bf16x8*>(
                                     reinterpret_cast<const char*>(dl) + byte);
                acc = __builtin_amdgcn_mfma_f32_32x32x16_bf16(a, bq[ks], acc, 0, 0, 0);
            }
#pragma unroll
            for (int p = 0; p < 4; ++p) {
                const int i4 = tloc + p * 8 + g * 4;
                const float v0 = (i4 + 0 < cr1) ? acc[4 * p + 0] : -9999.0f;
                const float v1 = (i4 + 1 < cr1) ? acc[4 * p + 1] : -9999.0f;
                const float v2 = (i4 + 2 < cr1) ? acc[4 * p + 2] : -9999.0f;
                const float v3 = (i4 + 3 < cr1) ? acc[4 * p + 3] : -9999.0f;
                best = fmaxf(best, fmaxf(fmaxf(v0, v1), fmaxf(v2, v3)));
            }
        }
    }

    // combine the two k-group token-halves (lanes l and l^32 share q=col)
    best = fmaxf(best, __shfl_xor(best, 32, 64));

    // ---- cross-wave max, then sum over q ----
    if (lane < 32) red[wave][col] = best;
    __syncthreads();

    if (tid < QLEN) {
        float m = red[0][tid];
#pragma unroll
        for (int w = 1; w < NWAVES; ++w) m = fmaxf(m, red[w][tid]);
#pragma unroll
        for (int off = 16; off > 0; off >>= 1) m += __shfl_xor(m, off, 32);
        if (tid == 0) out[b] = m;
    }
}

extern "C" void kernel_launch(void* const* d_in, const int* in_sizes, int n_in,
                              void* d_out, int out_size, void* d_ws, size_t ws_size,
                              hipStream_t stream)
{
    const float* Q  = (const float*)d_in[0];
    const float* D  = (const float*)d_in[1];
    const int*   Dm = (const int*)d_in[2];
    float* outp = (float*)d_out;
    const int ndocs = out_size;   // B*NWAY = 1024
    colbert_mfma<<<ndocs, NWAVES * 64, 0, stream>>>(Q, D, Dm, outp);
}

// Round 9
// 19.950 us; speedup vs baseline: 1.4345x; 1.0890x over previous
//
#include <hip/hip_runtime.h>

// ColBERT maxsim via MFMA + masked-row compaction + deep-issue staging.
// out[b] = sum_q max_k ( mask[b,k] ? <D[b,k,:], Q[b/8,q,:]> : -9999 )
// B*NWAY=1024 docs, DLEN=220, QLEN=32, DIM=128.
//
// Round-8 lesson: compaction halved bytes (115->58 MB) but effective HBM rate
// fell 4.45->2.76 TB/s: the stage loop was rolled (runtime trip count,
// list-dependent addresses, 2 loads/iter) -> shallow in-flight queue; 16
// waves/CU x ~3 outstanding can't cover ~900cy HBM latency on scattered rows.
// Round-9: (1) mask load FIRST (heads the dep chain), Q loads under it;
// (2) row indices list->registers, then two fully-unrolled 8-deep load
// batches (always-issue, clamped row; only the LDS write is predicated);
// (3) nc==0 guard.
//
// Skeleton: 256 thr / 4 waves / 4 blocks/CU; chunk0 = first min(nc,128) kept
// rows (covers ~99.3% of docs), rare chunk1 for nc>128. XOR swizzle
// byte ^= ((row&7)<<4) on 256B bf16 LDS rows kills the 32-way ds_read_b128
// bank conflict. Q fragments: direct strided loads (R7: LDS-staging Q = null).
// MFMA mfma_f32_32x32x16_bf16; same k-map for A and B => layout-safe.
// C/D layout (m74/m101): col(q)=lane&31, row(token)=(reg&3)+8*(reg>>2)+4*g.

#define QLEN   32
#define DIM    128
#define DLEN   220
#define NWAVES 4
#define C0MAX  128

typedef __attribute__((ext_vector_type(8)))  short bf16x8;
typedef __attribute__((ext_vector_type(16))) float f32x16;

__device__ __forceinline__ short f2bf(float f) {
    __bf16 h = (__bf16)f;                      // RNE hardware convert
    return __builtin_bit_cast(short, h);
}

__device__ __forceinline__ short4 cvt4(const float4& v) {
    short4 s;
    s.x = f2bf(v.x); s.y = f2bf(v.y); s.z = f2bf(v.z); s.w = f2bf(v.w);
    return s;
}

__device__ __forceinline__ bf16x8 cvt8(const float4& a, const float4& b) {
    bf16x8 r;
    r[0] = f2bf(a.x); r[1] = f2bf(a.y); r[2] = f2bf(a.z); r[3] = f2bf(a.w);
    r[4] = f2bf(b.x); r[5] = f2bf(b.y); r[6] = f2bf(b.z); r[7] = f2bf(b.w);
    return r;
}

__global__ __launch_bounds__(256, 4)
void colbert_mfma(const float* __restrict__ Q,
                  const float* __restrict__ D,
                  const int*   __restrict__ Dm,
                  float* __restrict__ out)
{
    // XCD swizzle (bijective: gridDim.x = 1024 % 8 == 0): docs sharing a Q
    // tile land on one XCD's L2.
    const int cpx = gridDim.x >> 3;
    const int o   = blockIdx.x;
    const int b   = (o & 7) * cpx + (o >> 3);

    const int tid  = threadIdx.x;
    const int wave = tid >> 6;
    const int lane = tid & 63;
    const int qb   = b >> 3;            // nway = 8

    const int col = lane & 31;          // A row-in-tile / B col (q)
    const int g   = lane >> 5;          // k-group

    __shared__ __align__(16) short dl[C0MAX * DIM];   // 32 KB staged bf16 rows
    __shared__ short list[DLEN + 4];                   // compacted row indices
    __shared__ int   wcnt[NWAVES];
    __shared__ int   s_nc;
    __shared__ float red[NWAVES][QLEN];

    const float* __restrict__ dbase = D + (size_t)b * DLEN * DIM;

    // ---- 1. mask load FIRST: it heads the dependency chain ----
    int mv = 0;
    if (tid < DLEN) mv = Dm[(size_t)b * DLEN + tid];

    // ---- 2. Q loads issued under the mask latency ----
    const float* __restrict__ qrow = Q + ((size_t)qb * QLEN + col) * DIM;
    float4 qx[8], qy[8];
#pragma unroll
    for (int ks = 0; ks < 8; ++ks) {
        qx[ks] = *reinterpret_cast<const float4*>(qrow + ks * 16 + g * 8);
        qy[ks] = *reinterpret_cast<const float4*>(qrow + ks * 16 + g * 8 + 4);
    }

    // ---- 3. compact kept row indices (order-preserving) ----
    const unsigned long long bal = __ballot(mv > 0);
    const int prefix = __popcll(bal & ((1ull << lane) - 1ull));
    if (lane == 0) wcnt[wave] = __popcll(bal);
    __syncthreads();
    int base = 0;
#pragma unroll
    for (int w = 0; w < NWAVES; ++w) base += (w < wave) ? wcnt[w] : 0;
    if (mv > 0) list[base + prefix] = (short)tid;
    if (tid == 0) s_nc = wcnt[0] + wcnt[1] + wcnt[2] + wcnt[3];

    // Q cvt overlaps the compaction barrier (frees 64 VGPR before D staging)
    bf16x8 bq[8];
#pragma unroll
    for (int ks = 0; ks < 8; ++ks) bq[ks] = cvt8(qx[ks], qy[ks]);
    __syncthreads();

    const int nc = s_nc;                 // kept rows, ~Binom(220,1/2) ~ 110
    const int c0 = (nc < C0MAX) ? nc : C0MAX;

    float best = -9999.0f;

    if (c0 > 0) {
        const int nch = c0 * 32;         // 16B chunks in chunk0

        // ---- 4. row indices -> registers, then 2 x 8-deep unrolled issue ----
        short rrow[16];
#pragma unroll
        for (int u = 0; u < 16; ++u) {
            const int c = tid + u * 256;
            rrow[u] = list[(c < nch ? c : 0) >> 5];
        }
#pragma unroll
        for (int half = 0; half < 2; ++half) {
            float4 v[8];
#pragma unroll
            for (int u = 0; u < 8; ++u) {                 // dense 8-deep issue
                const int uu = half * 8 + u;
                const int cir = (tid + uu * 256) & 31;
                v[u] = *reinterpret_cast<const float4*>(
                           dbase + (size_t)rrow[uu] * DIM + cir * 4);
            }
#pragma unroll
            for (int u = 0; u < 8; ++u) {                 // predicated writes
                const int uu = half * 8 + u;
                const int c  = tid + uu * 256;
                if (c < nch) {
                    const int lr = c >> 5, cir = c & 31;
                    const int byte = lr * 256 + ((cir * 8) ^ ((lr & 7) << 4));
                    *reinterpret_cast<short4*>(reinterpret_cast<char*>(dl) + byte)
                        = cvt4(v[u]);
                }
            }
        }
        __syncthreads();

        // ---- 5. compute chunk0: ceil(c0/32) tiles, one per wave ----
        const int ntiles = (c0 + 31) >> 5;
        if (wave < ntiles) {
            const int tloc = wave * 32;
            int rloc = tloc + col;
            if (rloc >= c0) rloc = 0;              // clamp; rejected below
            const int rsw = (rloc & 7) << 4;
            f32x16 acc = {};
#pragma unroll
            for (int ks = 0; ks < 8; ++ks) {
                const int byte = rloc * 256 + ((ks * 32 + g * 16) ^ rsw);
                const bf16x8 a = *reinterpret_cast<const bf16x8*>(
                                     reinterpret_cast<const char*>(dl) + byte);
                acc = __builtin_amdgcn_mfma_f32_32x32x16_bf16(a, bq[ks], acc, 0, 0, 0);
            }
            // validity: compacted local index < c0 (mask already applied)
#pragma unroll
            for (int p = 0; p < 4; ++p) {
                const int i4 = tloc + p * 8 + g * 4;
                const float v0 = (i4 + 0 < c0) ? acc[4 * p + 0] : -9999.0f;
                const float v1 = (i4 + 1 < c0) ? acc[4 * p + 1] : -9999.0f;
                const float v2 = (i4 + 2 < c0) ? acc[4 * p + 2] : -9999.0f;
                const float v3 = (i4 + 3 < c0) ? acc[4 * p + 3] : -9999.0f;
                best = fmaxf(best, fmaxf(fmaxf(v0, v1), fmaxf(v2, v3)));
            }
        }
    }

    // ---- rare chunk1 (nc > 128; ~0.7% of docs): simple rolled flow ----
    const int cr1 = nc - c0;
    if (cr1 > 0) {
        __syncthreads();                 // chunk0 reads done before overwrite
        const int nch = cr1 * 32;
        for (int i = tid; i < nch; i += 256) {
            const int row = list[c0 + (i >> 5)], cir = i & 31;
            const float4 v = *reinterpret_cast<const float4*>(
                                 dbase + (size_t)row * DIM + cir * 4);
            const int lr = i >> 5;
            const int byte = lr * 256 + ((cir * 8) ^ ((lr & 7) << 4));
            *reinterpret_cast<short4*>(reinterpret_cast<char*>(dl) + byte) = cvt4(v);
        }
        __syncthreads();

        const int ntiles = (cr1 + 31) >> 5;
        if (wave < ntiles) {
            const int tloc = wave * 32;
            int rloc = tloc + col;
            if (rloc >= cr1) rloc = 0;
            const int rsw = (rloc & 7) << 4;
            f32x16 acc = {};
#pragma unroll
            for (int ks = 0; ks < 8; ++ks) {
                const int byte = rloc * 256 + ((ks * 32 + g * 16) ^ rsw);
                const bf16x8 a = *reinterpret_cast<const bf16x8*>(
                                     reinterpret_cast<const char*>(dl) + byte);
                acc = __builtin_amdgcn_mfma_f32_32x32x16_bf16(a, bq[ks], acc, 0, 0, 0);
            }
#pragma unroll
            for (int p = 0; p < 4; ++p) {
                const int i4 = tloc + p * 8 + g * 4;
                const float v0 = (i4 + 0 < cr1) ? acc[4 * p + 0] : -9999.0f;
                const float v1 = (i4 + 1 < cr1) ? acc[4 * p + 1] : -9999.0f;
                const float v2 = (i4 + 2 < cr1) ? acc[4 * p + 2] : -9999.0f;
                const float v3 = (i4 + 3 < cr1) ? acc[4 * p + 3] : -9999.0f;
                best = fmaxf(best, fmaxf(fmaxf(v0, v1), fmaxf(v2, v3)));
            }
        }
    }

    // combine the two k-group token-halves (lanes l and l^32 share q=col)
    best = fmaxf(best, __shfl_xor(best, 32, 64));

    // ---- cross-wave max, then sum over q ----
    if (lane < 32) red[wave][col] = best;
    __syncthreads();

    if (tid < QLEN) {
        float m = red[0][tid];
#pragma unroll
        for (int w = 1; w < NWAVES; ++w) m = fmaxf(m, red[w][tid]);
#pragma unroll
        for (int off = 16; off > 0; off >>= 1) m += __shfl_xor(m, off, 32);
        if (tid == 0) out[b] = m;
    }
}

extern "C" void kernel_launch(void* const* d_in, const int* in_sizes, int n_in,
                              void* d_out, int out_size, void* d_ws, size_t ws_size,
                              hipStream_t stream)
{
    const float* Q  = (const float*)d_in[0];
    const float* D  = (const float*)d_in[1];
    const int*   Dm = (const int*)d_in[2];
    float* outp = (float*)d_out;
    const int ndocs = out_size;   // B*NWAY = 1024
    colbert_mfma<<<ndocs, NWAVES * 64, 0, stream>>>(Q, D, Dm, outp);
}